// Round 1
// 1003.527 us; speedup vs baseline: 1.1133x; 1.1133x over previous
//
#include <hip/hip_runtime.h>

// ---------------------------------------------------------------------------
// KronFTLinear: out = x@W^T + b + sum_p g[n,p] * (x @ (150*kron(A_p,B_p))^T)
//   Kron trick: out_p[n,2r+a] = 150 * sum_c A_p[r,c]*y_pa[n,c],
//               y_pa[n,c] = B_p[a,0]*x[n,2c] + B_p[a,1]*x[n,2c+1]
//   Gate folded into Y (Zg = g[n,p]*Y), p concatenated along K:
//       out_pack[n,2r+a] = sum_{k<4096} Zg_a[n,k] * Acat[r,k]
//   R3: k_base/k_pack rebuilt on a 256x256-tile 8-wave pipelined core
//   (BK=32, double-buffered 64 KiB LDS, counted vmcnt(2), setprio around
//   MFMA, raw s_barrier -- no full waitcnt drain in the K-loop). k_pack is
//   a single M=16384 GEMM (Zg planes concat along M) with stride-2 RMW
//   epilogue; companion planes adjacent in the swizzled grid for L2 merge.
// Workspace layout (256 MiB):
//   [0,64K)      g[8192][2] f32
//   [64K,96K)    gate_m[2][4096] f32
//   [1M,17M)     Acat[2048][4096] bf16  (150/2^22 folded in)
//   [32M,96M)    xb[8192][4096] bf16
//   [96M,128M)   bwb[4096][4096] bf16
//   [128M,256M)  Zg[2][8192][4096] bf16   (index: a)
//   [128M,160M)  trig tables (overlap Zg; consumed by k_abuild before k_convx)
// ---------------------------------------------------------------------------

#define AS1 __attribute__((address_space(1)))
#define AS3 __attribute__((address_space(3)))

using bf16x8   = __attribute__((ext_vector_type(8))) __bf16;
using f32x4    = __attribute__((ext_vector_type(4))) float;
using ushort8v = __attribute__((ext_vector_type(8))) unsigned short;
using ushort4v = __attribute__((ext_vector_type(4))) unsigned short;

__device__ __forceinline__ unsigned short f2bf(float f) {
  unsigned int u = __float_as_uint(f);
  u += 0x7FFFu + ((u >> 16) & 1u);   // round-to-nearest-even
  return (unsigned short)(u >> 16);
}

__device__ __forceinline__ void gll16(void* lds, const void* g) {
  __builtin_amdgcn_global_load_lds((AS1 void*)(g), (AS3 void*)(lds), 16, 0, 0);
}

// ---------------- prep: gate_m[e][d]
__global__ void k_gatem(const float* __restrict__ gp, const int* __restrict__ gidx,
                        float* __restrict__ gatem, int NG) {
  int t = blockIdx.x * 256 + threadIdx.x;    // 8192 threads
  int e = t >> 12, d = t & 4095;
  float acc = 0.f;
  for (int k = 0; k < NG; k++) {
    int iv = gidx[k];
    int dk = iv & 4095;
    float th = (float)((d * dk) & 4095) * 1.5339807878856412e-3f;  // 2pi/4096
    float cv = __cosf(th);
    float v = gp[k] * cv;
    acc += ((e & (iv >> 12)) & 1) ? -v : v;
  }
  gatem[t] = acc * (1.f / 8192.f);
}

// ---------------- prep: trig tables, z = p*2 + isQ; [z][r(2048)][kk(2048)] bf16
__global__ void k_tables(const float* __restrict__ spec, const int* __restrict__ idx,
                         unsigned short* __restrict__ tbl, int NFP) {
  int z = blockIdx.y;
  int p = z >> 1, isQ = z & 1;
  int t = blockIdx.x * 256 + threadIdx.x;
  int r = t >> 11, kk = t & 2047;
  unsigned short v = 0;
  if (kk < 2 * NFP) {
    int j = (kk < NFP) ? kk : kk - NFP;
    int iv = idx[p * NFP + j];
    int f = isQ ? (iv & 2047) : (iv >> 11);
    float th = (float)((r * f) & 2047) * 3.0679615757712823e-3f;   // 2pi/2048
    float val = (kk < NFP) ? __cosf(th) : __sinf(th);
    if (isQ) {
      float s = spec[p * NFP + j];
      val *= (kk < NFP) ? s : -s;            // A = P_cos Q_cos^T - P_sin Q_sin^T
    }
    v = f2bf(val);
  }
  tbl[(size_t)z * 4194304 + t] = v;
}

// ---------------- prep: gate logits GEMV + softmax -> g[n][2]
__global__ void k_gate(const float* __restrict__ x, const float* __restrict__ gatem,
                       float* __restrict__ g) {
  int n = blockIdx.x * 4 + (threadIdx.x >> 6);
  int l = threadIdx.x & 63;
  const float4* xr  = (const float4*)(x + (size_t)n * 4096);
  const float4* g0p = (const float4*)(gatem);
  const float4* g1p = (const float4*)(gatem + 4096);
  float s0 = 0.f, s1 = 0.f;
  for (int t = 0; t < 16; t++) {
    int ii = l + (t << 6);
    float4 xv = xr[ii], a = g0p[ii], b = g1p[ii];
    s0 += xv.x * a.x + xv.y * a.y + xv.z * a.z + xv.w * a.w;
    s1 += xv.x * b.x + xv.y * b.y + xv.z * b.z + xv.w * b.w;
  }
  for (int off = 32; off > 0; off >>= 1) {
    s0 += __shfl_down(s0, off);
    s1 += __shfl_down(s1, off);
  }
  if (l == 0) {
    float mx = fmaxf(s0, s1);
    float e0 = __expf(s0 - mx), e1 = __expf(s1 - mx);
    float inv = 1.f / (e0 + e1);
    g[2 * n] = e0 * inv;
    g[2 * n + 1] = e1 * inv;
  }
}

// ---------------- prep: x->xb bf16; Zg[a][n][p*2048+c] = g[n,p]*(B[p,a,0]x[n,2c]+B[p,a,1]x[n,2c+1])
__global__ void k_convx(const float* __restrict__ x, unsigned short* __restrict__ xb,
                        unsigned short* __restrict__ Zg, const float* __restrict__ Bl,
                        const float* __restrict__ g) {
  size_t t = (size_t)blockIdx.x * 256 + threadIdx.x;   // < 4194304, 8 elems each
  const float4* xp = (const float4*)x + t * 2;
  float4 v0 = xp[0], v1 = xp[1];
  ushort8v xv;
  xv[0]=f2bf(v0.x); xv[1]=f2bf(v0.y); xv[2]=f2bf(v0.z); xv[3]=f2bf(v0.w);
  xv[4]=f2bf(v1.x); xv[5]=f2bf(v1.y); xv[6]=f2bf(v1.z); xv[7]=f2bf(v1.w);
  *(ushort8v*)(xb + t * 8) = xv;
  int n = (int)(t >> 9);
  int c0 = ((int)t & 511) * 4;
  float gg[2] = {g[2 * n], g[2 * n + 1]};
  float xe[4] = {v0.x, v0.z, v1.x, v1.z};
  float xo[4] = {v0.y, v0.w, v1.y, v1.w};
  #pragma unroll
  for (int pa = 0; pa < 4; pa++) {
    int p = pa >> 1, a = pa & 1;
    float b0 = Bl[pa * 2] * gg[p], b1 = Bl[pa * 2 + 1] * gg[p];
    ushort4v yv;
    #pragma unroll
    for (int c = 0; c < 4; c++) yv[c] = f2bf(b0 * xe[c] + b1 * xo[c]);
    *(ushort4v*)(Zg + (size_t)a * 33554432 + (size_t)n * 4096 + p * 2048 + c0) = yv;
  }
}

// ---------------- prep: base_w -> bf16
__global__ void k_convw(const float* __restrict__ w, unsigned short* __restrict__ wb) {
  size_t t = (size_t)blockIdx.x * 256 + threadIdx.x;   // < 2097152
  const float4* sp = (const float4*)w + t * 2;
  float4 v0 = sp[0], v1 = sp[1];
  ushort8v o;
  o[0]=f2bf(v0.x); o[1]=f2bf(v0.y); o[2]=f2bf(v0.z); o[3]=f2bf(v0.w);
  o[4]=f2bf(v1.x); o[5]=f2bf(v1.y); o[6]=f2bf(v1.z); o[7]=f2bf(v1.w);
  *(ushort8v*)(wb + t * 8) = o;
}

// ---------------- legacy MFMA GEMM core (used by k_abuild only)
__device__ __forceinline__ void gemm_core(
    const unsigned short* __restrict__ Amat, int lda,
    const unsigned short* __restrict__ Bmat, int ldb,
    int K, char* As, char* Bs, f32x4 acc[4][4]) {
  const int tid = threadIdx.x;
  const int w = tid >> 6, l = tid & 63;
  const int quad = l >> 4, l15 = l & 15;
  const int wm = (w >> 1) << 6, wn = (w & 1) << 6;

  int c1 = (w << 6) + l, c2 = c1 + 256;
  int r1 = c1 >> 2, q1 = (c1 & 3) ^ ((r1 >> 1) & 3);
  int r2 = c2 >> 2, q2 = (c2 & 3) ^ ((r2 >> 1) & 3);
  const unsigned short* aS1 = Amat + (size_t)r1 * lda + (q1 << 3);
  const unsigned short* aS2 = Amat + (size_t)r2 * lda + (q2 << 3);
  const unsigned short* bS1 = Bmat + (size_t)r1 * ldb + (q1 << 3);
  const unsigned short* bS2 = Bmat + (size_t)r2 * ldb + (q2 << 3);
  char* aD1 = As + (w << 10);
  char* aD2 = As + 4096 + (w << 10);
  char* bD1 = Bs + (w << 10);
  char* bD2 = Bs + 4096 + (w << 10);

  int aOff[4], bOff[4];
  #pragma unroll
  for (int i = 0; i < 4; i++) {
    int ra = wm + (i << 4) + l15;
    aOff[i] = (ra << 6) + ((quad ^ ((ra >> 1) & 3)) << 4);
    int rb = wn + (i << 4) + l15;
    bOff[i] = (rb << 6) + ((quad ^ ((rb >> 1) & 3)) << 4);
  }

  for (int kt = 0; kt < K; kt += 32) {
    __syncthreads();
    gll16(aD1, aS1); gll16(aD2, aS2);
    gll16(bD1, bS1); gll16(bD2, bS2);
    __syncthreads();
    bf16x8 af[4], bfv[4];
    #pragma unroll
    for (int i = 0; i < 4; i++) af[i]  = *(const bf16x8*)(As + aOff[i]);
    #pragma unroll
    for (int j = 0; j < 4; j++) bfv[j] = *(const bf16x8*)(Bs + bOff[j]);
    #pragma unroll
    for (int i = 0; i < 4; i++)
      #pragma unroll
      for (int j = 0; j < 4; j++)
        acc[i][j] = __builtin_amdgcn_mfma_f32_16x16x32_bf16(af[i], bfv[j], acc[i][j], 0, 0, 0);
    aS1 += 32; aS2 += 32; bS1 += 32; bS2 += 32;
  }
}

// ---------------- A-build GEMM: Acat[r][p*2048+c] = (150/2^22)*(P_p @ Q_p^T)[r][c]
__global__ __launch_bounds__(256, 2) void k_abuild(
    const unsigned short* __restrict__ tbl, unsigned short* __restrict__ Acat) {
  __shared__ __align__(16) char sm[16384];
  const int p = blockIdx.z;
  const unsigned short* P = tbl + (size_t)(2 * p) * 4194304;
  const unsigned short* Q = tbl + (size_t)(2 * p + 1) * 4194304;
  f32x4 acc[4][4];
  #pragma unroll
  for (int i = 0; i < 4; i++)
    #pragma unroll
    for (int j = 0; j < 4; j++) acc[i][j] = (f32x4){0.f, 0.f, 0.f, 0.f};
  const int m0 = blockIdx.x << 7, n0 = blockIdx.y << 7;
  gemm_core(P + (size_t)m0 * 2048, 2048, Q + (size_t)n0 * 2048, 2048, 2048,
            sm, sm + 8192, acc);
  const int tid = threadIdx.x, w = tid >> 6, l = tid & 63;
  const int quad = l >> 4, l15 = l & 15;
  const int wm = (w >> 1) << 6, wn = (w & 1) << 6;
  const float SC = 150.f / 4194304.f;
  unsigned short* Ap = Acat + (size_t)p * 2048;   // column block for this p
  #pragma unroll
  for (int j = 0; j < 4; j++) {
    int c = n0 + wn + (j << 4) + l15;
    #pragma unroll
    for (int i = 0; i < 4; i++) {
      int rb = m0 + wm + (i << 4) + (quad << 2);
      #pragma unroll
      for (int reg = 0; reg < 4; reg++)
        Ap[(size_t)(rb + reg) * 4096 + c] = f2bf(acc[i][j][reg] * SC);
    }
  }
}

// ---------------------------------------------------------------------------
// 256x256 8-wave pipelined core, K=4096 fixed, lda=ldb=4096, BK=32.
// LDS (static 64 KiB): buf b in {0,1}: A[256][32] @ b*32768, B[256][32] @ +16384.
// Content swizzle identical to gemm_core: slot g holds source granule
// q = g ^ ((row>>1)&3); frag read slot = quad ^ ((l15>>1)&3) (row-invariant).
// Phase schedule per iteration (tiles T0=2i in buf0, T1=2i+1 in buf1):
//   p1: ds_read all T0 frags | stage T1.B->buf1 | lgkm0 | MFMA i0..3 | bar
//   p2: stage T2.A->buf0 | MFMA i4..7 | vmcnt(2) | bar
//   p3: ds_read all T1 frags | stage T2.B->buf0 | lgkm0 | MFMA i0..3 | bar
//   p4: stage T3.A->buf1 | MFMA i4..7 | vmcnt(2) | bar
// Counted vmcnt(2) leaves the 2 newest global_load_lds in flight across the
// barrier (T4); region-freedom: every buffer region is staged >=1 barrier
// after its last lgkmcnt(0)-completed read.
// ---------------------------------------------------------------------------
__device__ __forceinline__ void gemm256(const unsigned short* __restrict__ Ap,
                                        const unsigned short* __restrict__ Bp,
                                        char* sm, f32x4 acc[8][4]) {
  const int tid = threadIdx.x;             // 0..511, 8 waves
  const int wid = tid >> 6, lane = tid & 63;
  const int quad = lane >> 4, l15 = lane & 15;
  const int wr = wid >> 2, wc = wid & 3;   // 2M x 4N wave grid
  // staging geometry: slot s = tid covers 128 rows x 4 granules per round
  const int srow = tid >> 2, g = tid & 3;
  const int q = g ^ ((srow >> 1) & 3);
  const size_t soff = (size_t)srow * 4096 + (size_t)(q << 3);
  // frag read bases (+i*1024 / +j*1024; compile-time offsets)
  const int slotx = (quad ^ ((l15 >> 1) & 3)) << 4;
  const int aB = (((wr << 7) + l15) << 6) + slotx;
  const int bB = (((wc << 6) + l15) << 6) + slotx + 16384;

#define STG(BUF, ISB, RR, KT)                                                  \
  gll16(sm + (BUF) * 32768 + (ISB) * 16384 + (RR) * 8192 + (wid << 10),        \
        ((ISB) ? Bp : Ap) + soff + (size_t)(RR) * 524288 + (KT))

  // prologue: T0.A, T0.B, T1.A  (6 loads); wait all but T1.A (2)
  STG(0, 0, 0, 0);  STG(0, 0, 1, 0);
  STG(0, 1, 0, 0);  STG(0, 1, 1, 0);
  STG(1, 0, 0, 32); STG(1, 0, 1, 32);
  asm volatile("s_waitcnt vmcnt(2)" ::: "memory");
  __builtin_amdgcn_s_barrier();

  bf16x8 af[8], bfv[4];
  for (int it = 0; it < 64; it++) {
    const int kt = it << 6;
    const bool pref = (it < 63);
    // ---- phase 1
    #pragma unroll
    for (int i = 0; i < 8; i++) af[i]  = *(const bf16x8*)(sm + aB + i * 1024);
    #pragma unroll
    for (int j = 0; j < 4; j++) bfv[j] = *(const bf16x8*)(sm + bB + j * 1024);
    STG(1, 1, 0, kt + 32); STG(1, 1, 1, kt + 32);
    asm volatile("s_waitcnt lgkmcnt(0)" ::: "memory");
    __builtin_amdgcn_s_setprio(1);
    #pragma unroll
    for (int i = 0; i < 4; i++)
      #pragma unroll
      for (int j = 0; j < 4; j++)
        acc[i][j] = __builtin_amdgcn_mfma_f32_16x16x32_bf16(af[i], bfv[j], acc[i][j], 0, 0, 0);
    __builtin_amdgcn_s_setprio(0);
    __builtin_amdgcn_s_barrier();
    // ---- phase 2
    if (pref) { STG(0, 0, 0, kt + 64); STG(0, 0, 1, kt + 64); }
    __builtin_amdgcn_s_setprio(1);
    #pragma unroll
    for (int i = 4; i < 8; i++)
      #pragma unroll
      for (int j = 0; j < 4; j++)
        acc[i][j] = __builtin_amdgcn_mfma_f32_16x16x32_bf16(af[i], bfv[j], acc[i][j], 0, 0, 0);
    __builtin_amdgcn_s_setprio(0);
    if (pref) asm volatile("s_waitcnt vmcnt(2)" ::: "memory");
    else      asm volatile("s_waitcnt vmcnt(0)" ::: "memory");
    __builtin_amdgcn_s_barrier();
    // ---- phase 3
    #pragma unroll
    for (int i = 0; i < 8; i++) af[i]  = *(const bf16x8*)(sm + 32768 + aB + i * 1024);
    #pragma unroll
    for (int j = 0; j < 4; j++) bfv[j] = *(const bf16x8*)(sm + 32768 + bB + j * 1024);
    if (pref) { STG(0, 1, 0, kt + 64); STG(0, 1, 1, kt + 64); }
    asm volatile("s_waitcnt lgkmcnt(0)" ::: "memory");
    __builtin_amdgcn_s_setprio(1);
    #pragma unroll
    for (int i = 0; i < 4; i++)
      #pragma unroll
      for (int j = 0; j < 4; j++)
        acc[i][j] = __builtin_amdgcn_mfma_f32_16x16x32_bf16(af[i], bfv[j], acc[i][j], 0, 0, 0);
    __builtin_amdgcn_s_setprio(0);
    __builtin_amdgcn_s_barrier();
    // ---- phase 4
    if (pref) { STG(1, 0, 0, kt + 96); STG(1, 0, 1, kt + 96); }
    __builtin_amdgcn_s_setprio(1);
    #pragma unroll
    for (int i = 4; i < 8; i++)
      #pragma unroll
      for (int j = 0; j < 4; j++)
        acc[i][j] = __builtin_amdgcn_mfma_f32_16x16x32_bf16(af[i], bfv[j], acc[i][j], 0, 0, 0);
    __builtin_amdgcn_s_setprio(0);
    if (pref) asm volatile("s_waitcnt vmcnt(2)" ::: "memory");
    __builtin_amdgcn_s_barrier();
  }
#undef STG
}

// ---------------- base GEMM: out = xb @ bwb^T + bias  (256^2 tiles, 512 blk)
__global__ __launch_bounds__(512, 2) void k_base(
    const unsigned short* __restrict__ xb, const unsigned short* __restrict__ wb,
    const float* __restrict__ bias, float* __restrict__ out) {
  __shared__ __align__(16) char sm[65536];
  // bijective XCD swizzle (512 blocks, 8 XCDs); within an XCD the o-tile
  // (weight) index varies fastest so co-resident blocks share the xb panel.
  int lid = blockIdx.x + (blockIdx.y << 4);
  int nl = ((lid & 7) << 6) + (lid >> 3);
  const int m0 = (nl >> 4) << 8, n0 = (nl & 15) << 8;
  f32x4 acc[8][4];
  #pragma unroll
  for (int i = 0; i < 8; i++)
    #pragma unroll
    for (int j = 0; j < 4; j++) acc[i][j] = (f32x4){0.f, 0.f, 0.f, 0.f};
  gemm256(xb + (size_t)m0 * 4096, wb + (size_t)n0 * 4096, sm, acc);
  const int tid = threadIdx.x, wid = tid >> 6, lane = tid & 63;
  const int quad = lane >> 4, l15 = lane & 15;
  const int wr = wid >> 2, wc = wid & 3;
  #pragma unroll
  for (int j = 0; j < 4; j++) {
    int o = n0 + (wc << 6) + (j << 4) + l15;
    float bv = bias[o];
    #pragma unroll
    for (int i = 0; i < 8; i++) {
      int mb = m0 + (wr << 7) + (i << 4) + (quad << 2);
      #pragma unroll
      for (int reg = 0; reg < 4; reg++)
        out[(size_t)(mb + reg) * 4096 + o] = acc[i][j][reg] + bv;
    }
  }
}

// ---------------- pack GEMM: out[n,2r+a] += (Zg @ Acat^T)[a*8192+n, r]
// Single M=16384 GEMM (planes concat along M). Companion blocks (a=0/1 of the
// same n,r tile) are adjacent in the swizzled grid -> same XCD, L2-merged RMW.
__global__ __launch_bounds__(512, 2) void k_pack(
    const unsigned short* __restrict__ Zg, const unsigned short* __restrict__ Acat,
    float* __restrict__ out) {
  __shared__ __align__(16) char sm[65536];
  int lid = blockIdx.x + (blockIdx.y << 3);          // grid (8, 64)
  int nl = ((lid & 7) << 6) + (lid >> 3);
  const int bx = nl & 7, by = nl >> 3;
  const int a = by & 1, nt = by >> 1;                // plane, n-tile
  const int r0 = bx << 8;
  f32x4 acc[8][4];
  #pragma unroll
  for (int i = 0; i < 8; i++)
    #pragma unroll
    for (int j = 0; j < 4; j++) acc[i][j] = (f32x4){0.f, 0.f, 0.f, 0.f};
  gemm256(Zg + ((size_t)(a << 13) + (size_t)(nt << 8)) * 4096,
          Acat + (size_t)r0 * 4096, sm, acc);
  const int tid = threadIdx.x, wid = tid >> 6, lane = tid & 63;
  const int quad = lane >> 4, l15 = lane & 15;
  const int wr = wid >> 2, wc = wid & 3;
  #pragma unroll
  for (int j = 0; j < 4; j++) {
    int r = r0 + (wc << 6) + (j << 4) + l15;
    #pragma unroll
    for (int i = 0; i < 8; i++) {
      int nb = (nt << 8) + (wr << 7) + (i << 4) + (quad << 2);
      #pragma unroll
      for (int reg = 0; reg < 4; reg++) {
        float* p = out + (size_t)(nb + reg) * 4096 + 2 * r + a;
        *p += acc[i][j][reg];
      }
    }
  }
}

// ---------------------------------------------------------------------------
extern "C" void kernel_launch(void* const* d_in, const int* in_sizes, int n_in,
                              void* d_out, int out_size, void* d_ws, size_t ws_size,
                              hipStream_t stream) {
  const float* x    = (const float*)d_in[0];
  const float* basw = (const float*)d_in[1];
  const float* basb = (const float*)d_in[2];
  const float* spec = (const float*)d_in[3];
  const float* Bl   = (const float*)d_in[4];
  const float* gp   = (const float*)d_in[5];
  const int*   idx  = (const int*)d_in[6];
  const int*   gidx = (const int*)d_in[7];
  const int NFP = in_sizes[3] / 2;   // 1000
  const int NG  = in_sizes[5];       // 819

  char* ws = (char*)d_ws;
  float*          gbuf  = (float*)(ws);
  float*          gatem = (float*)(ws + (64ull << 10));
  unsigned short* Acat  = (unsigned short*)(ws + (1ull << 20));
  unsigned short* xb    = (unsigned short*)(ws + (32ull << 20));
  unsigned short* bwb   = (unsigned short*)(ws + (96ull << 20));
  unsigned short* Zg    = (unsigned short*)(ws + (128ull << 20));
  unsigned short* tbl   = (unsigned short*)(ws + (128ull << 20)); // overlaps Zg (ordered)
  float* outp = (float*)d_out;

  k_gatem <<<32, 256, 0, stream>>>(gp, gidx, gatem, NG);
  k_tables<<<dim3(16384, 4), 256, 0, stream>>>(spec, idx, tbl, NFP);
  k_abuild<<<dim3(16, 16, 2), 256, 0, stream>>>(tbl, Acat);      // reads tbl
  k_gate  <<<2048, 256, 0, stream>>>(x, gatem, gbuf);            // g before convx
  k_convx <<<16384, 256, 0, stream>>>(x, xb, Zg, Bl, gbuf);      // overwrites tbl region
  k_convw <<<8192, 256, 0, stream>>>(basw, bwb);
  k_base  <<<dim3(16, 32), 512, 0, stream>>>(xb, bwb, basb, outp);
  k_pack  <<<dim3(8, 64), 512, 0, stream>>>(Zg, Acat, outp);
  (void)n_in; (void)out_size; (void)ws_size;
}

// Round 3
// 1001.541 us; speedup vs baseline: 1.1155x; 1.0020x over previous
//
#include <hip/hip_runtime.h>

// ---------------------------------------------------------------------------
// KronFTLinear: out = x@W^T + b + sum_p g[n,p] * (x @ (150*kron(A_p,B_p))^T)
//   Kron trick: out_p[n,2r+a] = 150 * sum_c A_p[r,c]*y_pa[n,c],
//               y_pa[n,c] = B_p[a,0]*x[n,2c] + B_p[a,1]*x[n,2c+1]
//   Gate folded into Y (Zg = g[n,p]*Y), p concatenated along K:
//       out_pack[n,2r+a] = sum_{k<4096} Zg_a[n,k] * Acat[r,k]
//   R5 (= R4 re-expressed without macro machinery): gemm256 is a 4-LDS-buffer
//   (128 KiB) pipeline. Tile t+3's A-unit staged in tile t phase 0, B-unit in
//   phase 1; steady-state vmcnt(8) once per tile => issue-to-wait distance
//   4-5 phases. Tail drains vmcnt(4)->(0) exactly (in-order VMEM retirement).
//   Hazard trace: stage of buf[(t-1)&3] is issued only after the barrier that
//   follows tile t-1's lgkmcnt(0)-completed reads of that buffer; reads of
//   buf[t&3] occur only after tile t-1's vmcnt(8) confirmed tile t's 4 loads.
//   LDS layout/swizzle/K-order identical to the R3 passing kernel =>
//   bit-identical numerics.
// Workspace layout (256 MiB):
//   [0,64K)      g[8192][2] f32
//   [64K,96K)    gate_m[2][4096] f32
//   [1M,17M)     Acat[2048][4096] bf16  (150/2^22 folded in)
//   [32M,96M)    xb[8192][4096] bf16
//   [96M,128M)   bwb[4096][4096] bf16
//   [128M,256M)  Zg[2][8192][4096] bf16   (index: a)
//   [128M,160M)  trig tables (overlap Zg; consumed by k_abuild before k_convx)
// ---------------------------------------------------------------------------

#define AS1 __attribute__((address_space(1)))
#define AS3 __attribute__((address_space(3)))

using bf16x8   = __attribute__((ext_vector_type(8))) __bf16;
using f32x4    = __attribute__((ext_vector_type(4))) float;
using ushort8v = __attribute__((ext_vector_type(8))) unsigned short;
using ushort4v = __attribute__((ext_vector_type(4))) unsigned short;

__device__ __forceinline__ unsigned short f2bf(float f) {
  unsigned int u = __float_as_uint(f);
  u += 0x7FFFu + ((u >> 16) & 1u);   // round-to-nearest-even
  return (unsigned short)(u >> 16);
}

__device__ __forceinline__ void gll16(void* lds, const void* g) {
  __builtin_amdgcn_global_load_lds((AS1 void*)(g), (AS3 void*)(lds), 16, 0, 0);
}

// ---------------- prep: gate_m[e][d]
__global__ void k_gatem(const float* __restrict__ gp, const int* __restrict__ gidx,
                        float* __restrict__ gatem, int NG) {
  int t = blockIdx.x * 256 + threadIdx.x;    // 8192 threads
  int e = t >> 12, d = t & 4095;
  float acc = 0.f;
  for (int k = 0; k < NG; k++) {
    int iv = gidx[k];
    int dk = iv & 4095;
    float th = (float)((d * dk) & 4095) * 1.5339807878856412e-3f;  // 2pi/4096
    float cv = __cosf(th);
    float v = gp[k] * cv;
    acc += ((e & (iv >> 12)) & 1) ? -v : v;
  }
  gatem[t] = acc * (1.f / 8192.f);
}

// ---------------- prep: trig tables, z = p*2 + isQ; [z][r(2048)][kk(2048)] bf16
__global__ void k_tables(const float* __restrict__ spec, const int* __restrict__ idx,
                         unsigned short* __restrict__ tbl, int NFP) {
  int z = blockIdx.y;
  int p = z >> 1, isQ = z & 1;
  int t = blockIdx.x * 256 + threadIdx.x;
  int r = t >> 11, kk = t & 2047;
  unsigned short v = 0;
  if (kk < 2 * NFP) {
    int j = (kk < NFP) ? kk : kk - NFP;
    int iv = idx[p * NFP + j];
    int f = isQ ? (iv & 2047) : (iv >> 11);
    float th = (float)((r * f) & 2047) * 3.0679615757712823e-3f;   // 2pi/2048
    float val = (kk < NFP) ? __cosf(th) : __sinf(th);
    if (isQ) {
      float s = spec[p * NFP + j];
      val *= (kk < NFP) ? s : -s;            // A = P_cos Q_cos^T - P_sin Q_sin^T
    }
    v = f2bf(val);
  }
  tbl[(size_t)z * 4194304 + t] = v;
}

// ---------------- prep: gate logits GEMV + softmax -> g[n][2]
__global__ void k_gate(const float* __restrict__ x, const float* __restrict__ gatem,
                       float* __restrict__ g) {
  int n = blockIdx.x * 4 + (threadIdx.x >> 6);
  int l = threadIdx.x & 63;
  const float4* xr  = (const float4*)(x + (size_t)n * 4096);
  const float4* g0p = (const float4*)(gatem);
  const float4* g1p = (const float4*)(gatem + 4096);
  float s0 = 0.f, s1 = 0.f;
  for (int t = 0; t < 16; t++) {
    int ii = l + (t << 6);
    float4 xv = xr[ii], a = g0p[ii], b = g1p[ii];
    s0 += xv.x * a.x + xv.y * a.y + xv.z * a.z + xv.w * a.w;
    s1 += xv.x * b.x + xv.y * b.y + xv.z * b.z + xv.w * b.w;
  }
  for (int off = 32; off > 0; off >>= 1) {
    s0 += __shfl_down(s0, off);
    s1 += __shfl_down(s1, off);
  }
  if (l == 0) {
    float mx = fmaxf(s0, s1);
    float e0 = __expf(s0 - mx), e1 = __expf(s1 - mx);
    float inv = 1.f / (e0 + e1);
    g[2 * n] = e0 * inv;
    g[2 * n + 1] = e1 * inv;
  }
}

// ---------------- prep: x->xb bf16; Zg[a][n][p*2048+c] = g[n,p]*(B[p,a,0]x[n,2c]+B[p,a,1]x[n,2c+1])
__global__ void k_convx(const float* __restrict__ x, unsigned short* __restrict__ xb,
                        unsigned short* __restrict__ Zg, const float* __restrict__ Bl,
                        const float* __restrict__ g) {
  size_t t = (size_t)blockIdx.x * 256 + threadIdx.x;   // < 4194304, 8 elems each
  const float4* xp = (const float4*)x + t * 2;
  float4 v0 = xp[0], v1 = xp[1];
  ushort8v xv;
  xv[0]=f2bf(v0.x); xv[1]=f2bf(v0.y); xv[2]=f2bf(v0.z); xv[3]=f2bf(v0.w);
  xv[4]=f2bf(v1.x); xv[5]=f2bf(v1.y); xv[6]=f2bf(v1.z); xv[7]=f2bf(v1.w);
  *(ushort8v*)(xb + t * 8) = xv;
  int n = (int)(t >> 9);
  int c0 = ((int)t & 511) * 4;
  float gg[2] = {g[2 * n], g[2 * n + 1]};
  float xe[4] = {v0.x, v0.z, v1.x, v1.z};
  float xo[4] = {v0.y, v0.w, v1.y, v1.w};
  #pragma unroll
  for (int pa = 0; pa < 4; pa++) {
    int p = pa >> 1, a = pa & 1;
    float b0 = Bl[pa * 2] * gg[p], b1 = Bl[pa * 2 + 1] * gg[p];
    ushort4v yv;
    #pragma unroll
    for (int c = 0; c < 4; c++) yv[c] = f2bf(b0 * xe[c] + b1 * xo[c]);
    *(ushort4v*)(Zg + (size_t)a * 33554432 + (size_t)n * 4096 + p * 2048 + c0) = yv;
  }
}

// ---------------- prep: base_w -> bf16
__global__ void k_convw(const float* __restrict__ w, unsigned short* __restrict__ wb) {
  size_t t = (size_t)blockIdx.x * 256 + threadIdx.x;   // < 2097152
  const float4* sp = (const float4*)w + t * 2;
  float4 v0 = sp[0], v1 = sp[1];
  ushort8v o;
  o[0]=f2bf(v0.x); o[1]=f2bf(v0.y); o[2]=f2bf(v0.z); o[3]=f2bf(v0.w);
  o[4]=f2bf(v1.x); o[5]=f2bf(v1.y); o[6]=f2bf(v1.z); o[7]=f2bf(v1.w);
  *(ushort8v*)(wb + t * 8) = o;
}

// ---------------- legacy MFMA GEMM core (used by k_abuild only)
__device__ __forceinline__ void gemm_core(
    const unsigned short* __restrict__ Amat, int lda,
    const unsigned short* __restrict__ Bmat, int ldb,
    int K, char* As, char* Bs, f32x4 acc[4][4]) {
  const int tid = threadIdx.x;
  const int w = tid >> 6, l = tid & 63;
  const int quad = l >> 4, l15 = l & 15;
  const int wm = (w >> 1) << 6, wn = (w & 1) << 6;

  int c1 = (w << 6) + l, c2 = c1 + 256;
  int r1 = c1 >> 2, q1 = (c1 & 3) ^ ((r1 >> 1) & 3);
  int r2 = c2 >> 2, q2 = (c2 & 3) ^ ((r2 >> 1) & 3);
  const unsigned short* aS1 = Amat + (size_t)r1 * lda + (q1 << 3);
  const unsigned short* aS2 = Amat + (size_t)r2 * lda + (q2 << 3);
  const unsigned short* bS1 = Bmat + (size_t)r1 * ldb + (q1 << 3);
  const unsigned short* bS2 = Bmat + (size_t)r2 * ldb + (q2 << 3);
  char* aD1 = As + (w << 10);
  char* aD2 = As + 4096 + (w << 10);
  char* bD1 = Bs + (w << 10);
  char* bD2 = Bs + 4096 + (w << 10);

  int aOff[4], bOff[4];
  #pragma unroll
  for (int i = 0; i < 4; i++) {
    int ra = wm + (i << 4) + l15;
    aOff[i] = (ra << 6) + ((quad ^ ((ra >> 1) & 3)) << 4);
    int rb = wn + (i << 4) + l15;
    bOff[i] = (rb << 6) + ((quad ^ ((rb >> 1) & 3)) << 4);
  }

  for (int kt = 0; kt < K; kt += 32) {
    __syncthreads();
    gll16(aD1, aS1); gll16(aD2, aS2);
    gll16(bD1, bS1); gll16(bD2, bS2);
    __syncthreads();
    bf16x8 af[4], bfv[4];
    #pragma unroll
    for (int i = 0; i < 4; i++) af[i]  = *(const bf16x8*)(As + aOff[i]);
    #pragma unroll
    for (int j = 0; j < 4; j++) bfv[j] = *(const bf16x8*)(Bs + bOff[j]);
    #pragma unroll
    for (int i = 0; i < 4; i++)
      #pragma unroll
      for (int j = 0; j < 4; j++)
        acc[i][j] = __builtin_amdgcn_mfma_f32_16x16x32_bf16(af[i], bfv[j], acc[i][j], 0, 0, 0);
    aS1 += 32; aS2 += 32; bS1 += 32; bS2 += 32;
  }
}

// ---------------- A-build GEMM: Acat[r][p*2048+c] = (150/2^22)*(P_p @ Q_p^T)[r][c]
__global__ __launch_bounds__(256, 2) void k_abuild(
    const unsigned short* __restrict__ tbl, unsigned short* __restrict__ Acat) {
  __shared__ __align__(16) char sm[16384];
  const int p = blockIdx.z;
  const unsigned short* P = tbl + (size_t)(2 * p) * 4194304;
  const unsigned short* Q = tbl + (size_t)(2 * p + 1) * 4194304;
  f32x4 acc[4][4];
  #pragma unroll
  for (int i = 0; i < 4; i++)
    #pragma unroll
    for (int j = 0; j < 4; j++) acc[i][j] = (f32x4){0.f, 0.f, 0.f, 0.f};
  const int m0 = blockIdx.x << 7, n0 = blockIdx.y << 7;
  gemm_core(P + (size_t)m0 * 2048, 2048, Q + (size_t)n0 * 2048, 2048, 2048,
            sm, sm + 8192, acc);
  const int tid = threadIdx.x, w = tid >> 6, l = tid & 63;
  const int quad = l >> 4, l15 = l & 15;
  const int wm = (w >> 1) << 6, wn = (w & 1) << 6;
  const float SC = 150.f / 4194304.f;
  unsigned short* Ap = Acat + (size_t)p * 2048;   // column block for this p
  #pragma unroll
  for (int j = 0; j < 4; j++) {
    int c = n0 + wn + (j << 4) + l15;
    #pragma unroll
    for (int i = 0; i < 4; i++) {
      int rb = m0 + wm + (i << 4) + (quad << 2);
      #pragma unroll
      for (int reg = 0; reg < 4; reg++)
        Ap[(size_t)(rb + reg) * 4096 + c] = f2bf(acc[i][j][reg] * SC);
    }
  }
}

// ---------------------------------------------------------------------------
// 256x256 8-wave pipelined core, K=4096, BK=32, FOUR LDS buffers (128 KiB).
// Buffer b (32 KiB @ b*32768): A[256][32] @ +0, B[256][32] @ +16384; content
// swizzle: slot s of row r holds granule s ^ ((r>>1)&3).
// ---------------------------------------------------------------------------

// stage one matrix unit (256 rows x 32 cols, 2 gll16 per thread) of tile
// buffer `buf`; `base` = A or B panel origin; kt in elements.
__device__ __forceinline__ void stg_unit(char* sm, const unsigned short* base,
                                         size_t soff, int wid, int buf, int isb,
                                         int kt) {
  char* d = sm + buf * 32768 + isb * 16384 + (wid << 10);
  gll16(d,        base + soff + kt);
  gll16(d + 8192, base + soff + 524288 + kt);
}

__device__ __forceinline__ void tile_step(
    char* sm, const unsigned short* __restrict__ Ap,
    const unsigned short* __restrict__ Bp, size_t soff,
    int aB, int bB, int wid, f32x4 (&acc)[8][4], int T, bool do_stg, int vm) {
  bf16x8 af[8], bfv[4];
  char* bb = sm + (T & 3) * 32768;
  #pragma unroll
  for (int i = 0; i < 4; i++) af[i]  = *(const bf16x8*)(bb + aB + i * 1024);
  #pragma unroll
  for (int j = 0; j < 4; j++) bfv[j] = *(const bf16x8*)(bb + bB + j * 1024);
  if (do_stg) stg_unit(sm, Ap, soff, wid, (T + 3) & 3, 0, (T + 3) << 5);
  __builtin_amdgcn_s_barrier();
  asm volatile("s_waitcnt lgkmcnt(0)" ::: "memory");
  __builtin_amdgcn_s_setprio(1);
  #pragma unroll
  for (int i = 0; i < 4; i++)
    #pragma unroll
    for (int j = 0; j < 4; j++)
      acc[i][j] = __builtin_amdgcn_mfma_f32_16x16x32_bf16(af[i], bfv[j], acc[i][j], 0, 0, 0);
  __builtin_amdgcn_s_setprio(0);
  __builtin_amdgcn_s_barrier();
  #pragma unroll
  for (int i = 4; i < 8; i++) af[i] = *(const bf16x8*)(bb + aB + i * 1024);
  if (do_stg) stg_unit(sm, Bp, soff, wid, (T + 3) & 3, 1, (T + 3) << 5);
  __builtin_amdgcn_s_barrier();
  asm volatile("s_waitcnt lgkmcnt(0)" ::: "memory");
  __builtin_amdgcn_s_setprio(1);
  #pragma unroll
  for (int i = 4; i < 8; i++)
    #pragma unroll
    for (int j = 0; j < 4; j++)
      acc[i][j] = __builtin_amdgcn_mfma_f32_16x16x32_bf16(af[i], bfv[j], acc[i][j], 0, 0, 0);
  __builtin_amdgcn_s_setprio(0);
  if (vm == 8)      asm volatile("s_waitcnt vmcnt(8)" ::: "memory");
  else if (vm == 4) asm volatile("s_waitcnt vmcnt(4)" ::: "memory");
  else              asm volatile("s_waitcnt vmcnt(0)" ::: "memory");
  __builtin_amdgcn_s_barrier();
}

__device__ __forceinline__ void gemm256(const unsigned short* __restrict__ Ap,
                                        const unsigned short* __restrict__ Bp,
                                        char* sm, f32x4 (&acc)[8][4]) {
  const int tid = threadIdx.x;             // 0..511, 8 waves
  const int wid = tid >> 6, lane = tid & 63;
  const int quad = lane >> 4, l15 = lane & 15;
  const int wr = wid >> 2, wc = wid & 3;   // 2M x 4N wave grid
  // staging geometry: thread covers (srow = tid>>2, granule slot g = tid&3)
  const int srow = tid >> 2, g = tid & 3;
  const int q = g ^ ((srow >> 1) & 3);
  const size_t soff = (size_t)srow * 4096 + (size_t)(q << 3);
  // frag read bases (+i*1024 / +j*1024; compile-time offsets)
  const int slotx = (quad ^ ((l15 >> 1) & 3)) << 4;
  const int aB = (((wr << 7) + l15) << 6) + slotx;
  const int bB = (((wc << 6) + l15) << 6) + slotx + 16384;

  // prologue: tiles 0..2 fully staged (12 loads); vmcnt(8) confirms tile 0,
  // leaves tiles 1,2 (8 loads) in flight.
  stg_unit(sm, Ap, soff, wid, 0, 0, 0);
  stg_unit(sm, Bp, soff, wid, 0, 1, 0);
  stg_unit(sm, Ap, soff, wid, 1, 0, 32);
  stg_unit(sm, Bp, soff, wid, 1, 1, 32);
  stg_unit(sm, Ap, soff, wid, 2, 0, 64);
  stg_unit(sm, Bp, soff, wid, 2, 1, 64);
  asm volatile("s_waitcnt vmcnt(8)" ::: "memory");
  __builtin_amdgcn_s_barrier();

  #pragma unroll 4
  for (int t = 0; t < 125; t++)
    tile_step(sm, Ap, Bp, soff, aB, bB, wid, acc, t, true, 8);
  tile_step(sm, Ap, Bp, soff, aB, bB, wid, acc, 125, false, 4);
  tile_step(sm, Ap, Bp, soff, aB, bB, wid, acc, 126, false, 0);
  tile_step(sm, Ap, Bp, soff, aB, bB, wid, acc, 127, false, 0);
}

// ---------------- base GEMM: out = xb @ bwb^T + bias  (256^2 tiles, 512 blk)
__global__ __launch_bounds__(512, 1) void k_base(
    const unsigned short* __restrict__ xb, const unsigned short* __restrict__ wb,
    const float* __restrict__ bias, float* __restrict__ out) {
  __shared__ __align__(16) char sm[131072];
  // bijective XCD swizzle (512 blocks, 8 XCDs); within an XCD the o-tile
  // (weight) index varies fastest so co-resident blocks share the xb panel.
  int lid = blockIdx.x + (blockIdx.y << 4);
  int nl = ((lid & 7) << 6) + (lid >> 3);
  const int m0 = (nl >> 4) << 8, n0 = (nl & 15) << 8;
  f32x4 acc[8][4];
  #pragma unroll
  for (int i = 0; i < 8; i++)
    #pragma unroll
    for (int j = 0; j < 4; j++) acc[i][j] = (f32x4){0.f, 0.f, 0.f, 0.f};
  gemm256(xb + (size_t)m0 * 4096, wb + (size_t)n0 * 4096, sm, acc);
  const int tid = threadIdx.x, wid = tid >> 6, lane = tid & 63;
  const int quad = lane >> 4, l15 = lane & 15;
  const int wr = wid >> 2, wc = wid & 3;
  #pragma unroll
  for (int j = 0; j < 4; j++) {
    int o = n0 + (wc << 6) + (j << 4) + l15;
    float bv = bias[o];
    #pragma unroll
    for (int i = 0; i < 8; i++) {
      int mb = m0 + (wr << 7) + (i << 4) + (quad << 2);
      #pragma unroll
      for (int reg = 0; reg < 4; reg++)
        out[(size_t)(mb + reg) * 4096 + o] = acc[i][j][reg] + bv;
    }
  }
}

// ---------------- pack GEMM: out[n,2r+a] += (Zg @ Acat^T)[a*8192+n, r]
// Single M=16384 GEMM (planes concat along M). Companion blocks (a=0/1 of the
// same n,r tile) are adjacent in the swizzled grid -> same XCD, L2-merged RMW.
__global__ __launch_bounds__(512, 1) void k_pack(
    const unsigned short* __restrict__ Zg, const unsigned short* __restrict__ Acat,
    float* __restrict__ out) {
  __shared__ __align__(16) char sm[131072];
  int lid = blockIdx.x + (blockIdx.y << 3);          // grid (8, 64)
  int nl = ((lid & 7) << 6) + (lid >> 3);
  const int bx = nl & 7, by = nl >> 3;
  const int a = by & 1, nt = by >> 1;                // plane, n-tile
  const int r0 = bx << 8;
  f32x4 acc[8][4];
  #pragma unroll
  for (int i = 0; i < 8; i++)
    #pragma unroll
    for (int j = 0; j < 4; j++) acc[i][j] = (f32x4){0.f, 0.f, 0.f, 0.f};
  gemm256(Zg + ((size_t)(a << 13) + (size_t)(nt << 8)) * 4096,
          Acat + (size_t)r0 * 4096, sm, acc);
  const int tid = threadIdx.x, wid = tid >> 6, lane = tid & 63;
  const int quad = lane >> 4, l15 = lane & 15;
  const int wr = wid >> 2, wc = wid & 3;
  #pragma unroll
  for (int j = 0; j < 4; j++) {
    int r = r0 + (wc << 6) + (j << 4) + l15;
    #pragma unroll
    for (int i = 0; i < 8; i++) {
      int nb = (nt << 8) + (wr << 7) + (i << 4) + (quad << 2);
      #pragma unroll
      for (int reg = 0; reg < 4; reg++) {
        float* p = out + (size_t)(nb + reg) * 4096 + 2 * r + a;
        *p += acc[i][j][reg];
      }
    }
  }
}

// ---------------------------------------------------------------------------
extern "C" void kernel_launch(void* const* d_in, const int* in_sizes, int n_in,
                              void* d_out, int out_size, void* d_ws, size_t ws_size,
                              hipStream_t stream) {
  const float* x    = (const float*)d_in[0];
  const float* basw = (const float*)d_in[1];
  const float* basb = (const float*)d_in[2];
  const float* spec = (const float*)d_in[3];
  const float* Bl   = (const float*)d_in[4];
  const float* gp   = (const float*)d_in[5];
  const int*   idx  = (const int*)d_in[6];
  const int*   gidx = (const int*)d_in[7];
  const int NFP = in_sizes[3] / 2;   // 1000
  const int NG  = in_sizes[5];       // 819

  char* ws = (char*)d_ws;
  float*          gbuf  = (float*)(ws);
  float*          gatem = (float*)(ws + (64ull << 10));
  unsigned short* Acat  = (unsigned short*)(ws + (1ull << 20));
  unsigned short* xb    = (unsigned short*)(ws + (32ull << 20));
  unsigned short* bwb   = (unsigned short*)(ws + (96ull << 20));
  unsigned short* Zg    = (unsigned short*)(ws + (128ull << 20));
  unsigned short* tbl   = (unsigned short*)(ws + (128ull << 20)); // overlaps Zg (ordered)
  float* outp = (float*)d_out;

  k_gatem <<<32, 256, 0, stream>>>(gp, gidx, gatem, NG);
  k_tables<<<dim3(16384, 4), 256, 0, stream>>>(spec, idx, tbl, NFP);
  k_abuild<<<dim3(16, 16, 2), 256, 0, stream>>>(tbl, Acat);      // reads tbl
  k_gate  <<<2048, 256, 0, stream>>>(x, gatem, gbuf);            // g before convx
  k_convx <<<16384, 256, 0, stream>>>(x, xb, Zg, Bl, gbuf);      // overwrites tbl region
  k_convw <<<8192, 256, 0, stream>>>(basw, bwb);
  k_base  <<<dim3(16, 32), 512, 0, stream>>>(xb, bwb, basb, outp);
  k_pack  <<<dim3(8, 64), 512, 0, stream>>>(Zg, Acat, outp);
  (void)n_in; (void)out_size; (void)ws_size;
}

// Round 4
// 1001.042 us; speedup vs baseline: 1.1161x; 1.0005x over previous
//
#include <hip/hip_runtime.h>

// ---------------------------------------------------------------------------
// KronFTLinear: out = x@W^T + b + sum_p g[n,p] * (x @ (150*kron(A_p,B_p))^T)
//   Kron trick: out_p[n,2r+a] = 150 * sum_c A_p[r,c]*y_pa[n,c],
//               y_pa[n,c] = B_p[a,0]*x[n,2c] + B_p[a,1]*x[n,2c+1]
//   Gate folded into Y (Zg = g[n,p]*Y), p concatenated along K:
//       out_pack[n,2r+a] = sum_{k<4096} Zg_a[n,k] * Acat[r,k]
//   R6: ONE barrier per K-tile (was 4). With 4 LDS buffers, the single
//   end-of-tile {lgkmcnt(0) vmcnt(8); s_barrier} establishes both hazards:
//     RAW: tile T's staging confirmed by every wave's vmcnt before the
//          end-of-(T-1) barrier (in-order VMEM retirement, 12 outstanding,
//          vmcnt(8) confirms tile T+1 at end of T).
//     WAR: tile T-1's ds_reads complete before the end-of-(T-1) barrier
//          (lgkmcnt(0) in the combined wait), so staging T+3 into
//          buf[(T-1)&3] after that barrier is safe.
//   All 12 ds_reads issue at tile top (bfv first) -> compiler emits
//   fine-grained lgkmcnt(N) per consuming MFMA; waves skew within the tile
//   so one wave's LDS drain overlaps another's MFMAs (m114 co-schedule).
//   LDS layout/swizzle/per-acc K-order identical => bit-identical numerics.
// Workspace layout (256 MiB):
//   [0,64K)      g[8192][2] f32
//   [64K,96K)    gate_m[2][4096] f32
//   [1M,17M)     Acat[2048][4096] bf16  (150/2^22 folded in)
//   [32M,96M)    xb[8192][4096] bf16
//   [96M,128M)   bwb[4096][4096] bf16
//   [128M,256M)  Zg[2][8192][4096] bf16   (index: a)
//   [128M,160M)  trig tables (overlap Zg; consumed by k_abuild before k_convx)
// ---------------------------------------------------------------------------

#define AS1 __attribute__((address_space(1)))
#define AS3 __attribute__((address_space(3)))

using bf16x8   = __attribute__((ext_vector_type(8))) __bf16;
using f32x4    = __attribute__((ext_vector_type(4))) float;
using ushort8v = __attribute__((ext_vector_type(8))) unsigned short;
using ushort4v = __attribute__((ext_vector_type(4))) unsigned short;

__device__ __forceinline__ unsigned short f2bf(float f) {
  unsigned int u = __float_as_uint(f);
  u += 0x7FFFu + ((u >> 16) & 1u);   // round-to-nearest-even
  return (unsigned short)(u >> 16);
}

__device__ __forceinline__ void gll16(void* lds, const void* g) {
  __builtin_amdgcn_global_load_lds((AS1 void*)(g), (AS3 void*)(lds), 16, 0, 0);
}

// ---------------- prep: gate_m[e][d]
__global__ void k_gatem(const float* __restrict__ gp, const int* __restrict__ gidx,
                        float* __restrict__ gatem, int NG) {
  int t = blockIdx.x * 256 + threadIdx.x;    // 8192 threads
  int e = t >> 12, d = t & 4095;
  float acc = 0.f;
  for (int k = 0; k < NG; k++) {
    int iv = gidx[k];
    int dk = iv & 4095;
    float th = (float)((d * dk) & 4095) * 1.5339807878856412e-3f;  // 2pi/4096
    float cv = __cosf(th);
    float v = gp[k] * cv;
    acc += ((e & (iv >> 12)) & 1) ? -v : v;
  }
  gatem[t] = acc * (1.f / 8192.f);
}

// ---------------- prep: trig tables, z = p*2 + isQ; [z][r(2048)][kk(2048)] bf16
__global__ void k_tables(const float* __restrict__ spec, const int* __restrict__ idx,
                         unsigned short* __restrict__ tbl, int NFP) {
  int z = blockIdx.y;
  int p = z >> 1, isQ = z & 1;
  int t = blockIdx.x * 256 + threadIdx.x;
  int r = t >> 11, kk = t & 2047;
  unsigned short v = 0;
  if (kk < 2 * NFP) {
    int j = (kk < NFP) ? kk : kk - NFP;
    int iv = idx[p * NFP + j];
    int f = isQ ? (iv & 2047) : (iv >> 11);
    float th = (float)((r * f) & 2047) * 3.0679615757712823e-3f;   // 2pi/2048
    float val = (kk < NFP) ? __cosf(th) : __sinf(th);
    if (isQ) {
      float s = spec[p * NFP + j];
      val *= (kk < NFP) ? s : -s;            // A = P_cos Q_cos^T - P_sin Q_sin^T
    }
    v = f2bf(val);
  }
  tbl[(size_t)z * 4194304 + t] = v;
}

// ---------------- prep: gate logits GEMV + softmax -> g[n][2]
__global__ void k_gate(const float* __restrict__ x, const float* __restrict__ gatem,
                       float* __restrict__ g) {
  int n = blockIdx.x * 4 + (threadIdx.x >> 6);
  int l = threadIdx.x & 63;
  const float4* xr  = (const float4*)(x + (size_t)n * 4096);
  const float4* g0p = (const float4*)(gatem);
  const float4* g1p = (const float4*)(gatem + 4096);
  float s0 = 0.f, s1 = 0.f;
  for (int t = 0; t < 16; t++) {
    int ii = l + (t << 6);
    float4 xv = xr[ii], a = g0p[ii], b = g1p[ii];
    s0 += xv.x * a.x + xv.y * a.y + xv.z * a.z + xv.w * a.w;
    s1 += xv.x * b.x + xv.y * b.y + xv.z * b.z + xv.w * b.w;
  }
  for (int off = 32; off > 0; off >>= 1) {
    s0 += __shfl_down(s0, off);
    s1 += __shfl_down(s1, off);
  }
  if (l == 0) {
    float mx = fmaxf(s0, s1);
    float e0 = __expf(s0 - mx), e1 = __expf(s1 - mx);
    float inv = 1.f / (e0 + e1);
    g[2 * n] = e0 * inv;
    g[2 * n + 1] = e1 * inv;
  }
}

// ---------------- prep: x->xb bf16; Zg[a][n][p*2048+c] = g[n,p]*(B[p,a,0]x[n,2c]+B[p,a,1]x[n,2c+1])
__global__ void k_convx(const float* __restrict__ x, unsigned short* __restrict__ xb,
                        unsigned short* __restrict__ Zg, const float* __restrict__ Bl,
                        const float* __restrict__ g) {
  size_t t = (size_t)blockIdx.x * 256 + threadIdx.x;   // < 4194304, 8 elems each
  const float4* xp = (const float4*)x + t * 2;
  float4 v0 = xp[0], v1 = xp[1];
  ushort8v xv;
  xv[0]=f2bf(v0.x); xv[1]=f2bf(v0.y); xv[2]=f2bf(v0.z); xv[3]=f2bf(v0.w);
  xv[4]=f2bf(v1.x); xv[5]=f2bf(v1.y); xv[6]=f2bf(v1.z); xv[7]=f2bf(v1.w);
  *(ushort8v*)(xb + t * 8) = xv;
  int n = (int)(t >> 9);
  int c0 = ((int)t & 511) * 4;
  float gg[2] = {g[2 * n], g[2 * n + 1]};
  float xe[4] = {v0.x, v0.z, v1.x, v1.z};
  float xo[4] = {v0.y, v0.w, v1.y, v1.w};
  #pragma unroll
  for (int pa = 0; pa < 4; pa++) {
    int p = pa >> 1, a = pa & 1;
    float b0 = Bl[pa * 2] * gg[p], b1 = Bl[pa * 2 + 1] * gg[p];
    ushort4v yv;
    #pragma unroll
    for (int c = 0; c < 4; c++) yv[c] = f2bf(b0 * xe[c] + b1 * xo[c]);
    *(ushort4v*)(Zg + (size_t)a * 33554432 + (size_t)n * 4096 + p * 2048 + c0) = yv;
  }
}

// ---------------- prep: base_w -> bf16
__global__ void k_convw(const float* __restrict__ w, unsigned short* __restrict__ wb) {
  size_t t = (size_t)blockIdx.x * 256 + threadIdx.x;   // < 2097152
  const float4* sp = (const float4*)w + t * 2;
  float4 v0 = sp[0], v1 = sp[1];
  ushort8v o;
  o[0]=f2bf(v0.x); o[1]=f2bf(v0.y); o[2]=f2bf(v0.z); o[3]=f2bf(v0.w);
  o[4]=f2bf(v1.x); o[5]=f2bf(v1.y); o[6]=f2bf(v1.z); o[7]=f2bf(v1.w);
  *(ushort8v*)(wb + t * 8) = o;
}

// ---------------- legacy MFMA GEMM core (used by k_abuild only)
__device__ __forceinline__ void gemm_core(
    const unsigned short* __restrict__ Amat, int lda,
    const unsigned short* __restrict__ Bmat, int ldb,
    int K, char* As, char* Bs, f32x4 acc[4][4]) {
  const int tid = threadIdx.x;
  const int w = tid >> 6, l = tid & 63;
  const int quad = l >> 4, l15 = l & 15;
  const int wm = (w >> 1) << 6, wn = (w & 1) << 6;

  int c1 = (w << 6) + l, c2 = c1 + 256;
  int r1 = c1 >> 2, q1 = (c1 & 3) ^ ((r1 >> 1) & 3);
  int r2 = c2 >> 2, q2 = (c2 & 3) ^ ((r2 >> 1) & 3);
  const unsigned short* aS1 = Amat + (size_t)r1 * lda + (q1 << 3);
  const unsigned short* aS2 = Amat + (size_t)r2 * lda + (q2 << 3);
  const unsigned short* bS1 = Bmat + (size_t)r1 * ldb + (q1 << 3);
  const unsigned short* bS2 = Bmat + (size_t)r2 * ldb + (q2 << 3);
  char* aD1 = As + (w << 10);
  char* aD2 = As + 4096 + (w << 10);
  char* bD1 = Bs + (w << 10);
  char* bD2 = Bs + 4096 + (w << 10);

  int aOff[4], bOff[4];
  #pragma unroll
  for (int i = 0; i < 4; i++) {
    int ra = wm + (i << 4) + l15;
    aOff[i] = (ra << 6) + ((quad ^ ((ra >> 1) & 3)) << 4);
    int rb = wn + (i << 4) + l15;
    bOff[i] = (rb << 6) + ((quad ^ ((rb >> 1) & 3)) << 4);
  }

  for (int kt = 0; kt < K; kt += 32) {
    __syncthreads();
    gll16(aD1, aS1); gll16(aD2, aS2);
    gll16(bD1, bS1); gll16(bD2, bS2);
    __syncthreads();
    bf16x8 af[4], bfv[4];
    #pragma unroll
    for (int i = 0; i < 4; i++) af[i]  = *(const bf16x8*)(As + aOff[i]);
    #pragma unroll
    for (int j = 0; j < 4; j++) bfv[j] = *(const bf16x8*)(Bs + bOff[j]);
    #pragma unroll
    for (int i = 0; i < 4; i++)
      #pragma unroll
      for (int j = 0; j < 4; j++)
        acc[i][j] = __builtin_amdgcn_mfma_f32_16x16x32_bf16(af[i], bfv[j], acc[i][j], 0, 0, 0);
    aS1 += 32; aS2 += 32; bS1 += 32; bS2 += 32;
  }
}

// ---------------- A-build GEMM: Acat[r][p*2048+c] = (150/2^22)*(P_p @ Q_p^T)[r][c]
__global__ __launch_bounds__(256, 2) void k_abuild(
    const unsigned short* __restrict__ tbl, unsigned short* __restrict__ Acat) {
  __shared__ __align__(16) char sm[16384];
  const int p = blockIdx.z;
  const unsigned short* P = tbl + (size_t)(2 * p) * 4194304;
  const unsigned short* Q = tbl + (size_t)(2 * p + 1) * 4194304;
  f32x4 acc[4][4];
  #pragma unroll
  for (int i = 0; i < 4; i++)
    #pragma unroll
    for (int j = 0; j < 4; j++) acc[i][j] = (f32x4){0.f, 0.f, 0.f, 0.f};
  const int m0 = blockIdx.x << 7, n0 = blockIdx.y << 7;
  gemm_core(P + (size_t)m0 * 2048, 2048, Q + (size_t)n0 * 2048, 2048, 2048,
            sm, sm + 8192, acc);
  const int tid = threadIdx.x, w = tid >> 6, l = tid & 63;
  const int quad = l >> 4, l15 = l & 15;
  const int wm = (w >> 1) << 6, wn = (w & 1) << 6;
  const float SC = 150.f / 4194304.f;
  unsigned short* Ap = Acat + (size_t)p * 2048;   // column block for this p
  #pragma unroll
  for (int j = 0; j < 4; j++) {
    int c = n0 + wn + (j << 4) + l15;
    #pragma unroll
    for (int i = 0; i < 4; i++) {
      int rb = m0 + wm + (i << 4) + (quad << 2);
      #pragma unroll
      for (int reg = 0; reg < 4; reg++)
        Ap[(size_t)(rb + reg) * 4096 + c] = f2bf(acc[i][j][reg] * SC);
    }
  }
}

// ---------------------------------------------------------------------------
// 256x256 8-wave pipelined core, K=4096, BK=32, FOUR LDS buffers (128 KiB).
// Buffer b (32 KiB @ b*32768): A[256][32] @ +0, B[256][32] @ +16384; content
// swizzle: slot s of row r holds granule s ^ ((r>>1)&3).
// ONE barrier per tile; see header comment for the hazard proof.
// ---------------------------------------------------------------------------

// stage one matrix unit (256 rows x 32 cols, 2 gll16 per thread) of tile
// buffer `buf`; `base` = A or B panel origin; kt in elements.
__device__ __forceinline__ void stg_unit(char* sm, const unsigned short* base,
                                         size_t soff, int wid, int buf, int isb,
                                         int kt) {
  char* d = sm + buf * 32768 + isb * 16384 + (wid << 10);
  gll16(d,        base + soff + kt);
  gll16(d + 8192, base + soff + 524288 + kt);
}

__device__ __forceinline__ void tile_step(
    char* sm, const unsigned short* __restrict__ Ap,
    const unsigned short* __restrict__ Bp, size_t soff,
    int aB, int bB, int wid, f32x4 (&acc)[8][4], int T, bool do_stg, int vm) {
  bf16x8 af[8], bfv[4];
  char* bb = sm + (T & 3) * 32768;
  // issue all 12 ds_reads up front; first MFMA's operands (af0,bfv0) first
  af[0] = *(const bf16x8*)(bb + aB);
  #pragma unroll
  for (int j = 0; j < 4; j++) bfv[j] = *(const bf16x8*)(bb + bB + j * 1024);
  #pragma unroll
  for (int i = 1; i < 8; i++) af[i] = *(const bf16x8*)(bb + aB + i * 1024);
  if (do_stg) {
    stg_unit(sm, Ap, soff, wid, (T + 3) & 3, 0, (T + 3) << 5);
    stg_unit(sm, Bp, soff, wid, (T + 3) & 3, 1, (T + 3) << 5);
  }
  __builtin_amdgcn_s_setprio(1);
  #pragma unroll
  for (int i = 0; i < 8; i++)
    #pragma unroll
    for (int j = 0; j < 4; j++)
      acc[i][j] = __builtin_amdgcn_mfma_f32_16x16x32_bf16(af[i], bfv[j], acc[i][j], 0, 0, 0);
  __builtin_amdgcn_s_setprio(0);
  // single end-of-tile fence: lgkm0 = this tile's ds_reads done (WAR safety
  // for next tile's staging); vmcnt(N) = tile T+1's staging confirmed (RAW).
  if (vm == 8)      asm volatile("s_waitcnt vmcnt(8) lgkmcnt(0)" ::: "memory");
  else if (vm == 4) asm volatile("s_waitcnt vmcnt(4) lgkmcnt(0)" ::: "memory");
  else              asm volatile("s_waitcnt vmcnt(0) lgkmcnt(0)" ::: "memory");
  __builtin_amdgcn_s_barrier();
}

__device__ __forceinline__ void gemm256(const unsigned short* __restrict__ Ap,
                                        const unsigned short* __restrict__ Bp,
                                        char* sm, f32x4 (&acc)[8][4]) {
  const int tid = threadIdx.x;             // 0..511, 8 waves
  const int wid = tid >> 6, lane = tid & 63;
  const int quad = lane >> 4, l15 = lane & 15;
  const int wr = wid >> 2, wc = wid & 3;   // 2M x 4N wave grid
  // staging geometry: thread covers (srow = tid>>2, granule slot g = tid&3)
  const int srow = tid >> 2, g = tid & 3;
  const int q = g ^ ((srow >> 1) & 3);
  const size_t soff = (size_t)srow * 4096 + (size_t)(q << 3);
  // frag read bases (+i*1024 / +j*1024; compile-time offsets)
  const int slotx = (quad ^ ((l15 >> 1) & 3)) << 4;
  const int aB = (((wr << 7) + l15) << 6) + slotx;
  const int bB = (((wc << 6) + l15) << 6) + slotx + 16384;

  // prologue: tiles 0..2 fully staged (12 loads); vmcnt(8) confirms tile 0,
  // leaves tiles 1,2 (8 loads) in flight.
  stg_unit(sm, Ap, soff, wid, 0, 0, 0);
  stg_unit(sm, Bp, soff, wid, 0, 1, 0);
  stg_unit(sm, Ap, soff, wid, 1, 0, 32);
  stg_unit(sm, Bp, soff, wid, 1, 1, 32);
  stg_unit(sm, Ap, soff, wid, 2, 0, 64);
  stg_unit(sm, Bp, soff, wid, 2, 1, 64);
  asm volatile("s_waitcnt vmcnt(8)" ::: "memory");
  __builtin_amdgcn_s_barrier();

  #pragma unroll 4
  for (int t = 0; t < 125; t++)
    tile_step(sm, Ap, Bp, soff, aB, bB, wid, acc, t, true, 8);
  tile_step(sm, Ap, Bp, soff, aB, bB, wid, acc, 125, false, 4);
  tile_step(sm, Ap, Bp, soff, aB, bB, wid, acc, 126, false, 0);
  tile_step(sm, Ap, Bp, soff, aB, bB, wid, acc, 127, false, 0);
}

// ---------------- base GEMM: out = xb @ bwb^T + bias  (256^2 tiles, 512 blk)
__global__ __launch_bounds__(512, 1) void k_base(
    const unsigned short* __restrict__ xb, const unsigned short* __restrict__ wb,
    const float* __restrict__ bias, float* __restrict__ out) {
  __shared__ __align__(16) char sm[131072];
  // bijective XCD swizzle (512 blocks, 8 XCDs); within an XCD the o-tile
  // (weight) index varies fastest so co-resident blocks share the xb panel.
  int lid = blockIdx.x + (blockIdx.y << 4);
  int nl = ((lid & 7) << 6) + (lid >> 3);
  const int m0 = (nl >> 4) << 8, n0 = (nl & 15) << 8;
  f32x4 acc[8][4];
  #pragma unroll
  for (int i = 0; i < 8; i++)
    #pragma unroll
    for (int j = 0; j < 4; j++) acc[i][j] = (f32x4){0.f, 0.f, 0.f, 0.f};
  gemm256(xb + (size_t)m0 * 4096, wb + (size_t)n0 * 4096, sm, acc);
  const int tid = threadIdx.x, wid = tid >> 6, lane = tid & 63;
  const int quad = lane >> 4, l15 = lane & 15;
  const int wr = wid >> 2, wc = wid & 3;
  #pragma unroll
  for (int j = 0; j < 4; j++) {
    int o = n0 + (wc << 6) + (j << 4) + l15;
    float bv = bias[o];
    #pragma unroll
    for (int i = 0; i < 8; i++) {
      int mb = m0 + (wr << 7) + (i << 4) + (quad << 2);
      #pragma unroll
      for (int reg = 0; reg < 4; reg++)
        out[(size_t)(mb + reg) * 4096 + o] = acc[i][j][reg] + bv;
    }
  }
}

// ---------------- pack GEMM: out[n,2r+a] += (Zg @ Acat^T)[a*8192+n, r]
// Single M=16384 GEMM (planes concat along M). Companion blocks (a=0/1 of the
// same n,r tile) are adjacent in the swizzled grid -> same XCD, L2-merged RMW.
__global__ __launch_bounds__(512, 1) void k_pack(
    const unsigned short* __restrict__ Zg, const unsigned short* __restrict__ Acat,
    float* __restrict__ out) {
  __shared__ __align__(16) char sm[131072];
  int lid = blockIdx.x + (blockIdx.y << 3);          // grid (8, 64)
  int nl = ((lid & 7) << 6) + (lid >> 3);
  const int bx = nl & 7, by = nl >> 3;
  const int a = by & 1, nt = by >> 1;                // plane, n-tile
  const int r0 = bx << 8;
  f32x4 acc[8][4];
  #pragma unroll
  for (int i = 0; i < 8; i++)
    #pragma unroll
    for (int j = 0; j < 4; j++) acc[i][j] = (f32x4){0.f, 0.f, 0.f, 0.f};
  gemm256(Zg + ((size_t)(a << 13) + (size_t)(nt << 8)) * 4096,
          Acat + (size_t)r0 * 4096, sm, acc);
  const int tid = threadIdx.x, wid = tid >> 6, lane = tid & 63;
  const int quad = lane >> 4, l15 = lane & 15;
  const int wr = wid >> 2, wc = wid & 3;
  #pragma unroll
  for (int j = 0; j < 4; j++) {
    int r = r0 + (wc << 6) + (j << 4) + l15;
    #pragma unroll
    for (int i = 0; i < 8; i++) {
      int nb = (nt << 8) + (wr << 7) + (i << 4) + (quad << 2);
      #pragma unroll
      for (int reg = 0; reg < 4; reg++) {
        float* p = out + (size_t)(nb + reg) * 4096 + 2 * r + a;
        *p += acc[i][j][reg];
      }
    }
  }
}

// ---------------------------------------------------------------------------
extern "C" void kernel_launch(void* const* d_in, const int* in_sizes, int n_in,
                              void* d_out, int out_size, void* d_ws, size_t ws_size,
                              hipStream_t stream) {
  const float* x    = (const float*)d_in[0];
  const float* basw = (const float*)d_in[1];
  const float* basb = (const float*)d_in[2];
  const float* spec = (const float*)d_in[3];
  const float* Bl   = (const float*)d_in[4];
  const float* gp   = (const float*)d_in[5];
  const int*   idx  = (const int*)d_in[6];
  const int*   gidx = (const int*)d_in[7];
  const int NFP = in_sizes[3] / 2;   // 1000
  const int NG  = in_sizes[5];       // 819

  char* ws = (char*)d_ws;
  float*          gbuf  = (float*)(ws);
  float*          gatem = (float*)(ws + (64ull << 10));
  unsigned short* Acat  = (unsigned short*)(ws + (1ull << 20));
  unsigned short* xb    = (unsigned short*)(ws + (32ull << 20));
  unsigned short* bwb   = (unsigned short*)(ws + (96ull << 20));
  unsigned short* Zg    = (unsigned short*)(ws + (128ull << 20));
  unsigned short* tbl   = (unsigned short*)(ws + (128ull << 20)); // overlaps Zg (ordered)
  float* outp = (float*)d_out;

  k_gatem <<<32, 256, 0, stream>>>(gp, gidx, gatem, NG);
  k_tables<<<dim3(16384, 4), 256, 0, stream>>>(spec, idx, tbl, NFP);
  k_abuild<<<dim3(16, 16, 2), 256, 0, stream>>>(tbl, Acat);      // reads tbl
  k_gate  <<<2048, 256, 0, stream>>>(x, gatem, gbuf);            // g before convx
  k_convx <<<16384, 256, 0, stream>>>(x, xb, Zg, Bl, gbuf);      // overwrites tbl region
  k_convw <<<8192, 256, 0, stream>>>(basw, bwb);
  k_base  <<<dim3(16, 32), 512, 0, stream>>>(xb, bwb, basb, outp);
  k_pack  <<<dim3(8, 64), 512, 0, stream>>>(Zg, Acat, outp);
  (void)n_in; (void)out_size; (void)ws_size;
}

// Round 6
// 995.495 us; speedup vs baseline: 1.1223x; 1.0056x over previous
//
#include <hip/hip_runtime.h>

// ---------------------------------------------------------------------------
// KronFTLinear: out = x@W^T + b + sum_p g[n,p] * (x @ (150*kron(A_p,B_p))^T)
//   Kron trick: out_p[n,2r+a] = 150 * sum_c A_p[r,c]*y_pa[n,c],
//               y_pa[n,c] = B_p[a,0]*x[n,2c] + B_p[a,1]*x[n,2c+1]
//   Gate folded into Y (Zg = g[n,p]*Y), p concatenated along K:
//       out_pack[n,2r+a] = sum_{k<4096} Zg_a[n,k] * Acat[r,k]
//   R8: k_pack/k_base use the R6 core (verified passing, 1-barrier/tile,
//   4 LDS buffers, counted vmcnt(8)). NEW: k_abuild ported from the old
//   m97-class 128^2 core (~320 TF @ N=2048, 128-block underfill) to a
//   128x256-tile clone of the pipelined core: A-unit 1 gll16, B-unit 2,
//   3 loads/tile, steady vmcnt(6), 4 x 24 KiB LDS buffers, K=2048.
//   Grid (16,8,2) = 256 blocks = full GPU. Same K-chain order and staged
//   values as before => bit-identical Acat => absmax unchanged.
// Workspace layout (256 MiB):
//   [0,64K)      g[8192][2] f32
//   [64K,96K)    gate_m[2][4096] f32
//   [1M,17M)     Acat[2048][4096] bf16  (150/2^22 folded in)
//   [32M,96M)    xb[8192][4096] bf16
//   [96M,128M)   bwb[4096][4096] bf16
//   [128M,256M)  Zg[2][8192][4096] bf16   (index: a)
//   [128M,160M)  trig tables (overlap Zg; consumed by k_abuild before k_convx)
// ---------------------------------------------------------------------------

#define AS1 __attribute__((address_space(1)))
#define AS3 __attribute__((address_space(3)))

using bf16x8   = __attribute__((ext_vector_type(8))) __bf16;
using f32x4    = __attribute__((ext_vector_type(4))) float;
using ushort8v = __attribute__((ext_vector_type(8))) unsigned short;
using ushort4v = __attribute__((ext_vector_type(4))) unsigned short;

__device__ __forceinline__ unsigned short f2bf(float f) {
  unsigned int u = __float_as_uint(f);
  u += 0x7FFFu + ((u >> 16) & 1u);   // round-to-nearest-even
  return (unsigned short)(u >> 16);
}

__device__ __forceinline__ void gll16(void* lds, const void* g) {
  __builtin_amdgcn_global_load_lds((AS1 void*)(g), (AS3 void*)(lds), 16, 0, 0);
}

// ---------------- prep: gate_m[e][d]
__global__ void k_gatem(const float* __restrict__ gp, const int* __restrict__ gidx,
                        float* __restrict__ gatem, int NG) {
  int t = blockIdx.x * 256 + threadIdx.x;    // 8192 threads
  int e = t >> 12, d = t & 4095;
  float acc = 0.f;
  for (int k = 0; k < NG; k++) {
    int iv = gidx[k];
    int dk = iv & 4095;
    float th = (float)((d * dk) & 4095) * 1.5339807878856412e-3f;  // 2pi/4096
    float cv = __cosf(th);
    float v = gp[k] * cv;
    acc += ((e & (iv >> 12)) & 1) ? -v : v;
  }
  gatem[t] = acc * (1.f / 8192.f);
}

// ---------------- prep: trig tables, z = p*2 + isQ; [z][r(2048)][kk(2048)] bf16
__global__ void k_tables(const float* __restrict__ spec, const int* __restrict__ idx,
                         unsigned short* __restrict__ tbl, int NFP) {
  int z = blockIdx.y;
  int p = z >> 1, isQ = z & 1;
  int t = blockIdx.x * 256 + threadIdx.x;
  int r = t >> 11, kk = t & 2047;
  unsigned short v = 0;
  if (kk < 2 * NFP) {
    int j = (kk < NFP) ? kk : kk - NFP;
    int iv = idx[p * NFP + j];
    int f = isQ ? (iv & 2047) : (iv >> 11);
    float th = (float)((r * f) & 2047) * 3.0679615757712823e-3f;   // 2pi/2048
    float val = (kk < NFP) ? __cosf(th) : __sinf(th);
    if (isQ) {
      float s = spec[p * NFP + j];
      val *= (kk < NFP) ? s : -s;            // A = P_cos Q_cos^T - P_sin Q_sin^T
    }
    v = f2bf(val);
  }
  tbl[(size_t)z * 4194304 + t] = v;
}

// ---------------- prep: gate logits GEMV + softmax -> g[n][2]
__global__ void k_gate(const float* __restrict__ x, const float* __restrict__ gatem,
                       float* __restrict__ g) {
  int n = blockIdx.x * 4 + (threadIdx.x >> 6);
  int l = threadIdx.x & 63;
  const float4* xr  = (const float4*)(x + (size_t)n * 4096);
  const float4* g0p = (const float4*)(gatem);
  const float4* g1p = (const float4*)(gatem + 4096);
  float s0 = 0.f, s1 = 0.f;
  for (int t = 0; t < 16; t++) {
    int ii = l + (t << 6);
    float4 xv = xr[ii], a = g0p[ii], b = g1p[ii];
    s0 += xv.x * a.x + xv.y * a.y + xv.z * a.z + xv.w * a.w;
    s1 += xv.x * b.x + xv.y * b.y + xv.z * b.z + xv.w * b.w;
  }
  for (int off = 32; off > 0; off >>= 1) {
    s0 += __shfl_down(s0, off);
    s1 += __shfl_down(s1, off);
  }
  if (l == 0) {
    float mx = fmaxf(s0, s1);
    float e0 = __expf(s0 - mx), e1 = __expf(s1 - mx);
    float inv = 1.f / (e0 + e1);
    g[2 * n] = e0 * inv;
    g[2 * n + 1] = e1 * inv;
  }
}

// ---------------- prep: x->xb bf16; Zg[a][n][p*2048+c] = g[n,p]*(B[p,a,0]x[n,2c]+B[p,a,1]x[n,2c+1])
__global__ void k_convx(const float* __restrict__ x, unsigned short* __restrict__ xb,
                        unsigned short* __restrict__ Zg, const float* __restrict__ Bl,
                        const float* __restrict__ g) {
  size_t t = (size_t)blockIdx.x * 256 + threadIdx.x;   // < 4194304, 8 elems each
  const float4* xp = (const float4*)x + t * 2;
  float4 v0 = xp[0], v1 = xp[1];
  ushort8v xv;
  xv[0]=f2bf(v0.x); xv[1]=f2bf(v0.y); xv[2]=f2bf(v0.z); xv[3]=f2bf(v0.w);
  xv[4]=f2bf(v1.x); xv[5]=f2bf(v1.y); xv[6]=f2bf(v1.z); xv[7]=f2bf(v1.w);
  *(ushort8v*)(xb + t * 8) = xv;
  int n = (int)(t >> 9);
  int c0 = ((int)t & 511) * 4;
  float gg[2] = {g[2 * n], g[2 * n + 1]};
  float xe[4] = {v0.x, v0.z, v1.x, v1.z};
  float xo[4] = {v0.y, v0.w, v1.y, v1.w};
  #pragma unroll
  for (int pa = 0; pa < 4; pa++) {
    int p = pa >> 1, a = pa & 1;
    float b0 = Bl[pa * 2] * gg[p], b1 = Bl[pa * 2 + 1] * gg[p];
    ushort4v yv;
    #pragma unroll
    for (int c = 0; c < 4; c++) yv[c] = f2bf(b0 * xe[c] + b1 * xo[c]);
    *(ushort4v*)(Zg + (size_t)a * 33554432 + (size_t)n * 4096 + p * 2048 + c0) = yv;
  }
}

// ---------------- prep: base_w -> bf16
__global__ void k_convw(const float* __restrict__ w, unsigned short* __restrict__ wb) {
  size_t t = (size_t)blockIdx.x * 256 + threadIdx.x;   // < 2097152
  const float4* sp = (const float4*)w + t * 2;
  float4 v0 = sp[0], v1 = sp[1];
  ushort8v o;
  o[0]=f2bf(v0.x); o[1]=f2bf(v0.y); o[2]=f2bf(v0.z); o[3]=f2bf(v0.w);
  o[4]=f2bf(v1.x); o[5]=f2bf(v1.y); o[6]=f2bf(v1.z); o[7]=f2bf(v1.w);
  *(ushort8v*)(wb + t * 8) = o;
}

// ---------------------------------------------------------------------------
// 256x256 8-wave pipelined core (k_base/k_pack), K=4096, BK=32, 4 LDS buffers
// (128 KiB). Buffer b (32 KiB @ b*32768): A[256][32] @ +0, B[256][32] @
// +16384; content swizzle: slot s of row r holds granule s ^ ((r>>1)&3).
// ONE barrier per tile: the end-of-tile {vmcnt(N) lgkmcnt(0); s_barrier}
// establishes RAW (tile T+1 staged, all waves) and WAR (this tile's reads
// done before buf[(T-1)&3] is restaged). Verified passing (R6).
// ---------------------------------------------------------------------------

__device__ __forceinline__ void stg_unit(char* sm, const unsigned short* base,
                                         size_t soff, int wid, int buf, int isb,
                                         int kt) {
  char* d = sm + buf * 32768 + isb * 16384 + (wid << 10);
  gll16(d,        base + soff + kt);
  gll16(d + 8192, base + soff + 524288 + kt);
}

__device__ __forceinline__ void tile_step(
    char* sm, const unsigned short* __restrict__ Ap,
    const unsigned short* __restrict__ Bp, size_t soff,
    int aB, int bB, int wid, f32x4 (&acc)[8][4], int T, bool do_stg, int vm) {
  bf16x8 af[8], bfv[4];
  char* bb = sm + (T & 3) * 32768;
  // issue all 12 ds_reads up front; first MFMA's operands (af0,bfv0) first
  af[0] = *(const bf16x8*)(bb + aB);
  #pragma unroll
  for (int j = 0; j < 4; j++) bfv[j] = *(const bf16x8*)(bb + bB + j * 1024);
  #pragma unroll
  for (int i = 1; i < 8; i++) af[i] = *(const bf16x8*)(bb + aB + i * 1024);
  if (do_stg) {
    stg_unit(sm, Ap, soff, wid, (T + 3) & 3, 0, (T + 3) << 5);
    stg_unit(sm, Bp, soff, wid, (T + 3) & 3, 1, (T + 3) << 5);
  }
  __builtin_amdgcn_s_setprio(1);
  #pragma unroll
  for (int i = 0; i < 8; i++)
    #pragma unroll
    for (int j = 0; j < 4; j++)
      acc[i][j] = __builtin_amdgcn_mfma_f32_16x16x32_bf16(af[i], bfv[j], acc[i][j], 0, 0, 0);
  __builtin_amdgcn_s_setprio(0);
  if (vm == 8)      asm volatile("s_waitcnt vmcnt(8) lgkmcnt(0)" ::: "memory");
  else if (vm == 4) asm volatile("s_waitcnt vmcnt(4) lgkmcnt(0)" ::: "memory");
  else              asm volatile("s_waitcnt vmcnt(0) lgkmcnt(0)" ::: "memory");
  __builtin_amdgcn_s_barrier();
}

__device__ __forceinline__ void gemm256(const unsigned short* __restrict__ Ap,
                                        const unsigned short* __restrict__ Bp,
                                        char* sm, f32x4 (&acc)[8][4]) {
  const int tid = threadIdx.x;             // 0..511, 8 waves
  const int wid = tid >> 6, lane = tid & 63;
  const int quad = lane >> 4, l15 = lane & 15;
  const int wr = wid >> 2, wc = wid & 3;   // 2M x 4N wave grid
  const int srow = tid >> 2, g = tid & 3;
  const int q = g ^ ((srow >> 1) & 3);
  const size_t soff = (size_t)srow * 4096 + (size_t)(q << 3);
  const int slotx = (quad ^ ((l15 >> 1) & 3)) << 4;
  const int aB = (((wr << 7) + l15) << 6) + slotx;
  const int bB = (((wc << 6) + l15) << 6) + slotx + 16384;

  stg_unit(sm, Ap, soff, wid, 0, 0, 0);
  stg_unit(sm, Bp, soff, wid, 0, 1, 0);
  stg_unit(sm, Ap, soff, wid, 1, 0, 32);
  stg_unit(sm, Bp, soff, wid, 1, 1, 32);
  stg_unit(sm, Ap, soff, wid, 2, 0, 64);
  stg_unit(sm, Bp, soff, wid, 2, 1, 64);
  asm volatile("s_waitcnt vmcnt(8)" ::: "memory");
  __builtin_amdgcn_s_barrier();

  #pragma unroll 4
  for (int t = 0; t < 125; t++)
    tile_step(sm, Ap, Bp, soff, aB, bB, wid, acc, t, true, 8);
  tile_step(sm, Ap, Bp, soff, aB, bB, wid, acc, 125, false, 4);
  tile_step(sm, Ap, Bp, soff, aB, bB, wid, acc, 126, false, 0);
  tile_step(sm, Ap, Bp, soff, aB, bB, wid, acc, 127, false, 0);
}

// ---------------------------------------------------------------------------
// 128x256-tile pipelined core for k_abuild: C(128x256) = A(128xK) @ B(256xK)^T,
// lda=ldb=2048, K=2048 (64 tiles). 4 LDS buffers x 24 KiB: A[128][32] @ +0
// (8 KiB), B[256][32] @ +8192 (16 KiB). 3 gll16/thread/tile (1 A + 2 B);
// steady vmcnt(6) confirms tile T+1 (9 outstanding -> 6). Same content
// swizzle and one-barrier-per-tile hazard structure as gemm256.
// Per wave: 64x64 output = acc[4][4]; 8 ds_read + 16 MFMA per tile.
// ---------------------------------------------------------------------------

__device__ __forceinline__ void abuild_tile(
    char* sm, const unsigned short* __restrict__ Pp,
    const unsigned short* __restrict__ Qp, size_t soff,
    int aB, int bB, int wid, f32x4 (&acc)[4][4], int T, bool do_stg, int vm) {
  bf16x8 af[4], bfv[4];
  char* bb = sm + (T & 3) * 24576;
  af[0] = *(const bf16x8*)(bb + aB);
  #pragma unroll
  for (int j = 0; j < 4; j++) bfv[j] = *(const bf16x8*)(bb + bB + j * 1024);
  #pragma unroll
  for (int i = 1; i < 4; i++) af[i] = *(const bf16x8*)(bb + aB + i * 1024);
  if (do_stg) {
    const int buf = (T + 3) & 3, kt = (T + 3) << 5;
    char* d = sm + buf * 24576;
    gll16(d + (wid << 10),        Pp + soff + kt);                 // A: rows 0..127
    gll16(d + 8192 + (wid << 10), Qp + soff + kt);                 // B: rows 0..127
    gll16(d + 16384 + (wid << 10), Qp + soff + 262144 + kt);       // B: rows 128..255
  }
  __builtin_amdgcn_s_setprio(1);
  #pragma unroll
  for (int i = 0; i < 4; i++)
    #pragma unroll
    for (int j = 0; j < 4; j++)
      acc[i][j] = __builtin_amdgcn_mfma_f32_16x16x32_bf16(af[i], bfv[j], acc[i][j], 0, 0, 0);
  __builtin_amdgcn_s_setprio(0);
  if (vm == 6)      asm volatile("s_waitcnt vmcnt(6) lgkmcnt(0)" ::: "memory");
  else if (vm == 3) asm volatile("s_waitcnt vmcnt(3) lgkmcnt(0)" ::: "memory");
  else              asm volatile("s_waitcnt vmcnt(0) lgkmcnt(0)" ::: "memory");
  __builtin_amdgcn_s_barrier();
}

// ---------------- A-build GEMM: Acat[r][p*2048+c] = (150/2^22)*(P_p @ Q_p^T)[r][c]
__global__ __launch_bounds__(512, 1) void k_abuild(
    const unsigned short* __restrict__ tbl, unsigned short* __restrict__ Acat) {
  __shared__ __align__(16) char sm[98304];
  const int p = blockIdx.z;
  const int m0 = blockIdx.x << 7;            // 16 M-tiles of 128
  const int n0 = blockIdx.y << 8;            // 8 N-tiles of 256
  const unsigned short* Pp = tbl + (size_t)(2 * p) * 4194304 + (size_t)m0 * 2048;
  const unsigned short* Qp = tbl + (size_t)(2 * p + 1) * 4194304 + (size_t)n0 * 2048;

  const int tid = threadIdx.x;
  const int wid = tid >> 6, lane = tid & 63;
  const int quad = lane >> 4, l15 = lane & 15;
  const int wr = wid >> 2, wc = wid & 3;     // 2M x 4N waves -> 64x64 each
  const int srow = tid >> 2, g = tid & 3;
  const int q = g ^ ((srow >> 1) & 3);
  const size_t soff = (size_t)srow * 2048 + (size_t)(q << 3);
  const int slotx = (quad ^ ((l15 >> 1) & 3)) << 4;
  const int aB = (((wr << 6) + l15) << 6) + slotx;           // A rows wr*64+i*16+l15
  const int bB = (((wc << 6) + l15) << 6) + slotx + 8192;    // B rows wc*64+j*16+l15

  f32x4 acc[4][4];
  #pragma unroll
  for (int i = 0; i < 4; i++)
    #pragma unroll
    for (int j = 0; j < 4; j++) acc[i][j] = (f32x4){0.f, 0.f, 0.f, 0.f};

  // prologue: stage tiles 0..2 (9 loads); vmcnt(6) confirms tile 0.
  #pragma unroll
  for (int t0 = 0; t0 < 3; t0++) {
    char* d = sm + t0 * 24576;
    const int kt = t0 << 5;
    gll16(d + (wid << 10),         Pp + soff + kt);
    gll16(d + 8192 + (wid << 10),  Qp + soff + kt);
    gll16(d + 16384 + (wid << 10), Qp + soff + 262144 + kt);
  }
  asm volatile("s_waitcnt vmcnt(6)" ::: "memory");
  __builtin_amdgcn_s_barrier();

  #pragma unroll 4
  for (int t = 0; t < 61; t++)
    abuild_tile(sm, Pp, Qp, soff, aB, bB, wid, acc, t, true, 6);
  abuild_tile(sm, Pp, Qp, soff, aB, bB, wid, acc, 61, false, 3);
  abuild_tile(sm, Pp, Qp, soff, aB, bB, wid, acc, 62, false, 0);
  abuild_tile(sm, Pp, Qp, soff, aB, bB, wid, acc, 63, false, 0);

  const float SC = 150.f / 4194304.f;
  unsigned short* Ap = Acat + (size_t)p * 2048;   // column block for this p
  #pragma unroll
  for (int j = 0; j < 4; j++) {
    int c = n0 + (wc << 6) + (j << 4) + l15;
    #pragma unroll
    for (int i = 0; i < 4; i++) {
      int rb = m0 + (wr << 6) + (i << 4) + (quad << 2);
      #pragma unroll
      for (int reg = 0; reg < 4; reg++)
        Ap[(size_t)(rb + reg) * 4096 + c] = f2bf(acc[i][j][reg] * SC);
    }
  }
}

// ---------------- base GEMM: out = xb @ bwb^T + bias  (256^2 tiles, 512 blk)
__global__ __launch_bounds__(512, 1) void k_base(
    const unsigned short* __restrict__ xb, const unsigned short* __restrict__ wb,
    const float* __restrict__ bias, float* __restrict__ out) {
  __shared__ __align__(16) char sm[131072];
  // bijective XCD swizzle (512 blocks, 8 XCDs); within an XCD the o-tile
  // (weight) index varies fastest so co-resident blocks share the xb panel.
  int lid = blockIdx.x + (blockIdx.y << 4);
  int nl = ((lid & 7) << 6) + (lid >> 3);
  const int m0 = (nl >> 4) << 8, n0 = (nl & 15) << 8;
  f32x4 acc[8][4];
  #pragma unroll
  for (int i = 0; i < 8; i++)
    #pragma unroll
    for (int j = 0; j < 4; j++) acc[i][j] = (f32x4){0.f, 0.f, 0.f, 0.f};
  gemm256(xb + (size_t)m0 * 4096, wb + (size_t)n0 * 4096, sm, acc);
  const int tid = threadIdx.x, wid = tid >> 6, lane = tid & 63;
  const int quad = lane >> 4, l15 = lane & 15;
  const int wr = wid >> 2, wc = wid & 3;
  #pragma unroll
  for (int j = 0; j < 4; j++) {
    int o = n0 + (wc << 6) + (j << 4) + l15;
    float bv = bias[o];
    #pragma unroll
    for (int i = 0; i < 8; i++) {
      int mb = m0 + (wr << 7) + (i << 4) + (quad << 2);
      #pragma unroll
      for (int reg = 0; reg < 4; reg++)
        out[(size_t)(mb + reg) * 4096 + o] = acc[i][j][reg] + bv;
    }
  }
}

// ---------------- pack GEMM: out[n,2r+a] += (Zg @ Acat^T)[a*8192+n, r]
// Single M=16384 GEMM (planes concat along M). Companion blocks (a=0/1 of the
// same n,r tile) are adjacent in the swizzled grid -> same XCD, L2-merged RMW.
__global__ __launch_bounds__(512, 1) void k_pack(
    const unsigned short* __restrict__ Zg, const unsigned short* __restrict__ Acat,
    float* __restrict__ out) {
  __shared__ __align__(16) char sm[131072];
  int lid = blockIdx.x + (blockIdx.y << 3);          // grid (8, 64)
  int nl = ((lid & 7) << 6) + (lid >> 3);
  const int bx = nl & 7, by = nl >> 3;
  const int a = by & 1, nt = by >> 1;                // plane, n-tile
  const int r0 = bx << 8;
  f32x4 acc[8][4];
  #pragma unroll
  for (int i = 0; i < 8; i++)
    #pragma unroll
    for (int j = 0; j < 4; j++) acc[i][j] = (f32x4){0.f, 0.f, 0.f, 0.f};
  gemm256(Zg + ((size_t)(a << 13) + (size_t)(nt << 8)) * 4096,
          Acat + (size_t)r0 * 4096, sm, acc);
  const int tid = threadIdx.x, wid = tid >> 6, lane = tid & 63;
  const int quad = lane >> 4, l15 = lane & 15;
  const int wr = wid >> 2, wc = wid & 3;
  #pragma unroll
  for (int j = 0; j < 4; j++) {
    int r = r0 + (wc << 6) + (j << 4) + l15;
    #pragma unroll
    for (int i = 0; i < 8; i++) {
      int nb = (nt << 8) + (wr << 7) + (i << 4) + (quad << 2);
      #pragma unroll
      for (int reg = 0; reg < 4; reg++) {
        float* p = out + (size_t)(nb + reg) * 4096 + 2 * r + a;
        *p += acc[i][j][reg];
      }
    }
  }
}

// ---------------------------------------------------------------------------
extern "C" void kernel_launch(void* const* d_in, const int* in_sizes, int n_in,
                              void* d_out, int out_size, void* d_ws, size_t ws_size,
                              hipStream_t stream) {
  const float* x    = (const float*)d_in[0];
  const float* basw = (const float*)d_in[1];
  const float* basb = (const float*)d_in[2];
  const float* spec = (const float*)d_in[3];
  const float* Bl   = (const float*)d_in[4];
  const float* gp   = (const float*)d_in[5];
  const int*   idx  = (const int*)d_in[6];
  const int*   gidx = (const int*)d_in[7];
  const int NFP = in_sizes[3] / 2;   // 1000
  const int NG  = in_sizes[5];       // 819

  char* ws = (char*)d_ws;
  float*          gbuf  = (float*)(ws);
  float*          gatem = (float*)(ws + (64ull << 10));
  unsigned short* Acat  = (unsigned short*)(ws + (1ull << 20));
  unsigned short* xb    = (unsigned short*)(ws + (32ull << 20));
  unsigned short* bwb   = (unsigned short*)(ws + (96ull << 20));
  unsigned short* Zg    = (unsigned short*)(ws + (128ull << 20));
  unsigned short* tbl   = (unsigned short*)(ws + (128ull << 20)); // overlaps Zg (ordered)
  float* outp = (float*)d_out;

  k_gatem <<<32, 256, 0, stream>>>(gp, gidx, gatem, NG);
  k_tables<<<dim3(16384, 4), 256, 0, stream>>>(spec, idx, tbl, NFP);
  k_abuild<<<dim3(16, 8, 2), 512, 0, stream>>>(tbl, Acat);       // reads tbl
  k_gate  <<<2048, 256, 0, stream>>>(x, gatem, gbuf);            // g before convx
  k_convx <<<16384, 256, 0, stream>>>(x, xb, Zg, Bl, gbuf);      // overwrites tbl region
  k_convw <<<8192, 256, 0, stream>>>(basw, bwb);
  k_base  <<<dim3(16, 32), 512, 0, stream>>>(xb, bwb, basb, outp);
  k_pack  <<<dim3(8, 64), 512, 0, stream>>>(Zg, Acat, outp);
  (void)n_in; (void)out_size; (void)ws_size;
}